// Round 10
// baseline (435.350 us; speedup 1.0000x reference)
//
#include <hip/hip_runtime.h>
#include <hip/hip_bf16.h>

#define NN 100000   // nodes
#define NNP 100032  // NN padded to 64
#define HH 4        // heads
#define DD 64       // dim per head
#define RR 2        // relations
#define EE 500000   // edges per relation
#define KK 256      // in_feat
#define HD 256      // H*D
#define HD2 512     // both relations' features per node
#define NEG_SLOPE 0.2f

typedef __attribute__((ext_vector_type(8))) short bfx8;
typedef __attribute__((ext_vector_type(4))) float f32x4;
typedef __attribute__((ext_vector_type(2))) __fp16 h2;

__device__ __forceinline__ ushort f2bf(float f){
    __hip_bfloat16 h = __float2bfloat16(f);
    return *(ushort*)&h;
}
__device__ __forceinline__ float bf2f(ushort u){
    return __uint_as_float(((unsigned)u) << 16);
}
__device__ __forceinline__ bfx8 cvt8(float4 v0, float4 v1){
    bfx8 a;
    a[0]=(short)f2bf(v0.x); a[1]=(short)f2bf(v0.y);
    a[2]=(short)f2bf(v0.z); a[3]=(short)f2bf(v0.w);
    a[4]=(short)f2bf(v1.x); a[5]=(short)f2bf(v1.y);
    a[6]=(short)f2bf(v1.z); a[7]=(short)f2bf(v1.w);
    return a;
}

// wcatbT[j][k] = bf16( sum_d W[k][h*64+d]*attn[h][d] ), j = r*8 + s*4 + h
__global__ void k_wcat(const float* __restrict__ Ws, const float* __restrict__ Wd,
                       const float* __restrict__ al, const float* __restrict__ ar,
                       ushort* __restrict__ wcatbT){
    int gid = blockIdx.x*blockDim.x + threadIdx.x;
    if (gid >= KK*16) return;
    int k = gid >> 4, j = gid & 15;
    int r = j >> 3, s = (j >> 2) & 1, h = j & 3;
    const float* w = (s ? Wd : Ws) + ((size_t)r*KK + k)*HD + h*DD;
    const float* a = (s ? ar : al) + (size_t)(r*HH + h)*DD;
    float acc = 0.f;
    #pragma unroll 8
    for (int d=0; d<DD; ++d) acc += w[d]*a[d];
    wcatbT[(size_t)j*KK + k] = f2bf(acc);
}

// Wt[r*256+n][k] = bf16(W_src[r][k][n])  — transposed, both relations stacked
__global__ void k_castW(const float* __restrict__ W, ushort* __restrict__ Wt){
    int gid = blockIdx.x*blockDim.x + threadIdx.x;
    if (gid >= RR*KK*HD) return;
    int r = gid >> 16;
    int idx = gid & 65535;
    int n = idx >> 8, k = idx & 255;
    Wt[gid] = f2bf(W[((size_t)r*KK + k)*HD + n]);
}

// eall = bf16MFMA(x @ wcat) [N,16]; one wave per 16 rows
__global__ __launch_bounds__(256) void k_eall(const float* __restrict__ x,
                                              const ushort* __restrict__ wcatbT,
                                              float* __restrict__ eall){
    int w = threadIdx.x >> 6, lane = threadIdx.x & 63;
    int n0 = blockIdx.x*64 + w*16;
    int r16 = lane & 15, ksub = lane >> 4;
    int row = n0 + r16;
    int rowc = row < NN ? row : NN-1;
    const float* xr = x + (size_t)rowc*KK;
    f32x4 acc = {};
    #pragma unroll
    for (int kk = 0; kk < 8; ++kk){
        int kb = ksub*8 + kk*32;
        float4 v0 = *(const float4*)(xr + kb);
        float4 v1 = *(const float4*)(xr + kb + 4);
        bfx8 a = cvt8(v0, v1);
        bfx8 b = *(const bfx8*)(wcatbT + (size_t)r16*KK + kb);
        acc = __builtin_amdgcn_mfma_f32_16x16x32_bf16(a, b, acc, 0, 0, 0);
    }
    #pragma unroll
    for (int i = 0; i < 4; ++i){
        int nr = n0 + ksub*4 + i;
        if (nr < NN) eall[(size_t)nr*16 + r16] = acc[i];
    }
}

__global__ void k_hist(const int* __restrict__ didx, unsigned* __restrict__ cnt){
    int gid = blockIdx.x*blockDim.x + threadIdx.x;
    if (gid >= RR*EE) return;
    int r = gid / EE;
    atomicAdd(&cnt[(size_t)r*NN + didx[gid]], 1u);
}

// segment base allocation: wave-scan + one cursor atomic per wave (order-free CSR)
__global__ void k_alloc(const unsigned* __restrict__ cnt, unsigned* __restrict__ base,
                        unsigned* __restrict__ cursor){
    int gid = blockIdx.x*blockDim.x + threadIdx.x;
    int lane = threadIdx.x & 63;
    unsigned c = (gid < RR*NN) ? cnt[gid] : 0u;
    unsigned x = c;
    #pragma unroll
    for (int off = 1; off < 64; off <<= 1){
        unsigned t = __shfl_up(x, off, 64);
        if (lane >= off) x += t;
    }
    unsigned wtotal = __shfl(x, 63, 64);
    unsigned wbase = 0u;
    if (lane == 63) wbase = atomicAdd(cursor, wtotal);
    wbase = __shfl(wbase, 63, 64);
    if (gid < RR*NN) base[gid] = wbase + x - c;
}

// scatter src + packed f16 el[4 heads] into dst-grouped slots
__global__ void k_scatter(const int* __restrict__ sidx, const int* __restrict__ didx,
                          const float* __restrict__ eall,
                          const unsigned* __restrict__ base, unsigned* __restrict__ cur,
                          int* __restrict__ esrc, uint2* __restrict__ epak){
    int gid = blockIdx.x*blockDim.x + threadIdx.x;
    if (gid >= RR*EE) return;
    int r = gid / EE;
    int s = sidx[gid];
    size_t rn = (size_t)r*NN + didx[gid];
    unsigned pos = base[rn] + atomicAdd(&cur[rn], 1u);
    esrc[pos] = s;
    float4 e4 = *(const float4*)(eall + (size_t)s*16 + r*8);
    h2 p0 = __builtin_amdgcn_cvt_pkrtz(e4.x, e4.y);
    h2 p1 = __builtin_amdgcn_cvt_pkrtz(e4.z, e4.w);
    uint2 u;
    u.x = *(unsigned*)&p0; u.y = *(unsigned*)&p1;
    epak[pos] = u;
}

// bf16 MFMA GEMM: fsall[M,512] = x[M,256] @ Wt^T (both relations).
// A: f32 reg-staged -> bf16, swizzled ds_write. B: global_load_lds, pre-swizzled src.
__global__ __launch_bounds__(256) void k_gemm(const float* __restrict__ Ax,
                                              const ushort* __restrict__ Bt,
                                              ushort* __restrict__ C){
    __shared__ ushort Ab[128*64];
    __shared__ ushort Bb[128*64];
    int tid = threadIdx.x;
    int w = tid >> 6, lane = tid & 63;
    int m0 = blockIdx.x * 128;
    int n0 = blockIdx.y * 128;
    int wm = w >> 1, wn = w & 1;      // 2x2 wave grid, 64x64 per wave
    f32x4 acc[4][4] = {};
    int srow  = lane >> 3;            // row within 8-row chunk
    int sunit = (lane & 7) ^ srow;    // pre-swizzled source 16B unit

    for (int k0 = 0; k0 < KK; k0 += 64){
        // stage A: f32 -> bf16, swizzled ds_write_b64
        #pragma unroll
        for (int i = 0; i < 8; ++i){
            int flat = tid + 256*i;           // 0..2047
            int row  = flat >> 4;             // 0..127
            int q    = flat & 15;             // float4 index within row
            int arw = m0 + row; if (arw >= NN) arw = NN-1;
            float4 v = *(const float4*)(Ax + (size_t)arw*KK + k0 + q*4);
            ushort4 b;
            b.x = f2bf(v.x); b.y = f2bf(v.y); b.z = f2bf(v.z); b.w = f2bf(v.w);
            int usw = (q >> 1) ^ (row & 7);
            *(ushort4*)((char*)Ab + row*128 + usw*16 + (q & 1)*8) = b;
        }
        // stage B: global_load_lds 16B, wave-uniform LDS base, pre-swizzled source
        #pragma unroll
        for (int i = 0; i < 4; ++i){
            int rowl = i*32 + w*8 + srow;     // n-index 0..127 (per-lane source row)
            const ushort* gb = Bt + (size_t)(n0 + rowl)*KK + k0 + sunit*8;
            __builtin_amdgcn_global_load_lds(
                (const __attribute__((address_space(1))) void*)gb,
                (__attribute__((address_space(3))) void*)(Bb + (i*32 + w*8)*64),
                16, 0, 0);
        }
        __syncthreads();
        #pragma unroll
        for (int kk = 0; kk < 64; kk += 32){
            bfx8 af[4], bfr[4];
            int r16 = lane & 15;
            int ublk = (lane >> 4) + (kk >> 3);   // logical 16B unit 0..7
            #pragma unroll
            for (int m = 0; m < 4; ++m){
                int row = wm*64 + m*16 + r16;
                af[m] = *(const bfx8*)(Ab + row*64 + ((ublk ^ (row & 7)) << 3));
            }
            #pragma unroll
            for (int n = 0; n < 4; ++n){
                int col = wn*64 + n*16 + r16;
                bfr[n] = *(const bfx8*)(Bb + col*64 + ((ublk ^ (col & 7)) << 3));
            }
            #pragma unroll
            for (int m = 0; m < 4; ++m)
                #pragma unroll
                for (int n = 0; n < 4; ++n)
                    acc[m][n] = __builtin_amdgcn_mfma_f32_16x16x32_bf16(
                                    af[m], bfr[n], acc[m][n], 0, 0, 0);
        }
        __syncthreads();
    }
    // epilogue: C/D layout col=lane&15, row=(lane>>4)*4+i ; store bf16, stride 512
    int cr = lane >> 4, cc = lane & 15;
    #pragma unroll
    for (int m = 0; m < 4; ++m){
        #pragma unroll
        for (int i = 0; i < 4; ++i){
            int row = m0 + wm*64 + m*16 + cr*4 + i;
            #pragma unroll
            for (int n = 0; n < 4; ++n)
                C[(size_t)row*HD2 + n0 + wn*64 + n*16 + cc] = f2bf(acc[m][n][i]);
        }
    }
}

// one wave per node, both relations; feature-per-lane (4 f32/lane).
// 8-edge unroll (one burst covers mean degree 5), 4 accumulator banks (t&3).
// el from packed f16 stream (plain cached loads — nt loads were a measured
// regression in R8: broadcast/sequential small reads need L1/L2).
// No-max softmax (logits bounded ~±6). Non-temporal OUT store only.
__global__ __launch_bounds__(256) void k_agg(const unsigned* __restrict__ base,
                                             const unsigned* __restrict__ cnt,
                                             const int* __restrict__ esrc,
                                             const uint2* __restrict__ epak,
                                             const float* __restrict__ eall,
                                             const ushort* __restrict__ fsall,
                                             const float* __restrict__ bias,
                                             float* __restrict__ out){
    int w = threadIdx.x >> 6, lane = threadIdx.x & 63;
    int n = blockIdx.x*4 + w;
    int h = lane >> 4;
    float rx = 0.f, ry = 0.f, rz = 0.f, rw = 0.f;
    #pragma unroll
    for (int r = 0; r < RR; ++r){
        unsigned beg = base[(size_t)r*NN + n], num = cnt[(size_t)r*NN + n];
        float er = eall[(size_t)n*16 + r*8 + 4 + h];
        float ax[4] = {0,0,0,0}, ay[4] = {0,0,0,0};
        float az[4] = {0,0,0,0}, aw[4] = {0,0,0,0};
        float dn[4] = {0,0,0,0};
        for (unsigned u0 = 0; u0 < num; u0 += 8){
            #pragma unroll
            for (int t = 0; t < 8; ++t){
                unsigned o = u0 + (unsigned)t;
                bool valid = o < num;
                unsigned idx = beg + (valid ? o : 0u);
                int s = esrc[idx];
                uint2 ep = epak[idx];
                unsigned wsel = (h & 2) ? ep.y : ep.x;
                ushort hv = (h & 1) ? (ushort)(wsel >> 16) : (ushort)wsel;
                __fp16 hf = *(__fp16*)&hv;
                float v = (float)hf + er;
                v = v > 0.f ? v : NEG_SLOPE*v;
                float p = valid ? __expf(v) : 0.f;
                ushort4 f = *(const ushort4*)(fsall + (size_t)s*HD2 + r*HD + lane*4);
                int b = t & 3;
                dn[b] += p;
                ax[b] += p*bf2f(f.x); ay[b] += p*bf2f(f.y);
                az[b] += p*bf2f(f.z); aw[b] += p*bf2f(f.w);
            }
        }
        float den = (dn[0]+dn[1]) + (dn[2]+dn[3]);
        float inv = den > 0.f ? 1.f/den : 0.f;
        rx += ((ax[0]+ax[1])+(ax[2]+ax[3]))*inv;
        ry += ((ay[0]+ay[1])+(ay[2]+ay[3]))*inv;
        rz += ((az[0]+az[1])+(az[2]+az[3]))*inv;
        rw += ((aw[0]+aw[1])+(aw[2]+aw[3]))*inv;
    }
    const float4 b0 = *(const float4*)(bias + lane*4);
    const float4 b1 = *(const float4*)(bias + HD + lane*4);
    f32x4 res;
    res[0] = rx + b0.x + b1.x; res[1] = ry + b0.y + b1.y;
    res[2] = rz + b0.z + b1.z; res[3] = rw + b0.w + b1.w;
    __builtin_nontemporal_store(res, (f32x4*)(out + (size_t)n*HD + lane*4));
}

extern "C" void kernel_launch(void* const* d_in, const int* in_sizes, int n_in,
                              void* d_out, int out_size, void* d_ws, size_t ws_size,
                              hipStream_t stream) {
    const float* x     = (const float*)d_in[0];
    const float* W_src = (const float*)d_in[1];
    const float* W_dst = (const float*)d_in[2];
    const float* al    = (const float*)d_in[3];
    const float* ar    = (const float*)d_in[4];
    const float* bias  = (const float*)d_in[5];
    const int*   sidx  = (const int*)d_in[6];
    const int*   didx  = (const int*)d_in[7];
    float* out = (float*)d_out;

    // workspace carve-up (~123.5 MB)
    ushort*   fsall  = (ushort*)d_ws;                        // NNP*512 bf16
    ushort*   Wt     = fsall + (size_t)NNP*HD2;              // 512*256 bf16
    ushort*   wcatbT = Wt + (size_t)RR*KK*HD;                // 16*256 bf16
    float*    eall   = (float*)(wcatbT + 16*KK);             // N*16 f32
    unsigned* cnt    = (unsigned*)(eall + (size_t)NN*16);    // R*N
    unsigned* cur    = cnt + (size_t)RR*NN;                  // R*N
    unsigned* cursor = cur + (size_t)RR*NN;                  // 8 (1 + pad)
    unsigned* base   = cursor + 8;                           // R*N
    int*      esrc   = (int*)(base + (size_t)RR*NN);         // R*E ints
    uint2*    epak   = (uint2*)(esrc + (size_t)RR*EE);       // R*E uint2

    k_wcat<<<(KK*16 + 255)/256, 256, 0, stream>>>(W_src, W_dst, al, ar, wcatbT);
    k_castW<<<(RR*KK*HD + 255)/256, 256, 0, stream>>>(W_src, Wt);
    k_eall<<<(NNP + 63)/64, 256, 0, stream>>>(x, wcatbT, eall);
    k_gemm<<<dim3((NNP + 127)/128, HD2/128), 256, 0, stream>>>(x, Wt, fsall);

    (void)hipMemsetAsync(cnt, 0, (size_t)(2*RR*NN + 8)*4, stream);   // cnt, cur, cursor
    k_hist<<<(RR*EE + 255)/256, 256, 0, stream>>>(didx, cnt);
    k_alloc<<<(RR*NN + 255)/256, 256, 0, stream>>>(cnt, base, cursor);
    k_scatter<<<(RR*EE + 255)/256, 256, 0, stream>>>(sidx, didx, eall, base, cur, esrc, epak);

    k_agg<<<NN/4, 256, 0, stream>>>(base, cnt, esrc, epak, eall, fsall, bias, out);
}

// Round 11
// 372.845 us; speedup vs baseline: 1.1676x; 1.1676x over previous
//
#include <hip/hip_runtime.h>
#include <hip/hip_bf16.h>

#define NN 100000   // nodes
#define NNP 100032  // NN padded to 64
#define HH 4        // heads
#define DD 64       // dim per head
#define RR 2        // relations
#define EE 500000   // edges per relation
#define KK 256      // in_feat
#define HD 256      // H*D
#define HD2 512     // both relations' features per node
#define NEG_SLOPE 0.2f

typedef __attribute__((ext_vector_type(8))) short bfx8;
typedef __attribute__((ext_vector_type(4))) float f32x4;
typedef __attribute__((ext_vector_type(2))) __fp16 h2;

__device__ __forceinline__ ushort f2bf(float f){
    __hip_bfloat16 h = __float2bfloat16(f);
    return *(ushort*)&h;
}
__device__ __forceinline__ float bf2f(ushort u){
    return __uint_as_float(((unsigned)u) << 16);
}
__device__ __forceinline__ bfx8 cvt8(float4 v0, float4 v1){
    bfx8 a;
    a[0]=(short)f2bf(v0.x); a[1]=(short)f2bf(v0.y);
    a[2]=(short)f2bf(v0.z); a[3]=(short)f2bf(v0.w);
    a[4]=(short)f2bf(v1.x); a[5]=(short)f2bf(v1.y);
    a[6]=(short)f2bf(v1.z); a[7]=(short)f2bf(v1.w);
    return a;
}

// wcatbT[j][k] = bf16( sum_d W[k][h*64+d]*attn[h][d] ), j = r*8 + s*4 + h
__global__ void k_wcat(const float* __restrict__ Ws, const float* __restrict__ Wd,
                       const float* __restrict__ al, const float* __restrict__ ar,
                       ushort* __restrict__ wcatbT){
    int gid = blockIdx.x*blockDim.x + threadIdx.x;
    if (gid >= KK*16) return;
    int k = gid >> 4, j = gid & 15;
    int r = j >> 3, s = (j >> 2) & 1, h = j & 3;
    const float* w = (s ? Wd : Ws) + ((size_t)r*KK + k)*HD + h*DD;
    const float* a = (s ? ar : al) + (size_t)(r*HH + h)*DD;
    float acc = 0.f;
    #pragma unroll 8
    for (int d=0; d<DD; ++d) acc += w[d]*a[d];
    wcatbT[(size_t)j*KK + k] = f2bf(acc);
}

// Wt[r*256+n][k] = bf16(W_src[r][k][n])  — transposed, both relations stacked
__global__ void k_castW(const float* __restrict__ W, ushort* __restrict__ Wt){
    int gid = blockIdx.x*blockDim.x + threadIdx.x;
    if (gid >= RR*KK*HD) return;
    int r = gid >> 16;
    int idx = gid & 65535;
    int n = idx >> 8, k = idx & 255;
    Wt[gid] = f2bf(W[((size_t)r*KK + k)*HD + n]);
}

// eall = bf16MFMA(x @ wcat) [N,16]; one wave per 16 rows
__global__ __launch_bounds__(256) void k_eall(const float* __restrict__ x,
                                              const ushort* __restrict__ wcatbT,
                                              float* __restrict__ eall){
    int w = threadIdx.x >> 6, lane = threadIdx.x & 63;
    int n0 = blockIdx.x*64 + w*16;
    int r16 = lane & 15, ksub = lane >> 4;
    int row = n0 + r16;
    int rowc = row < NN ? row : NN-1;
    const float* xr = x + (size_t)rowc*KK;
    f32x4 acc = {};
    #pragma unroll
    for (int kk = 0; kk < 8; ++kk){
        int kb = ksub*8 + kk*32;
        float4 v0 = *(const float4*)(xr + kb);
        float4 v1 = *(const float4*)(xr + kb + 4);
        bfx8 a = cvt8(v0, v1);
        bfx8 b = *(const bfx8*)(wcatbT + (size_t)r16*KK + kb);
        acc = __builtin_amdgcn_mfma_f32_16x16x32_bf16(a, b, acc, 0, 0, 0);
    }
    #pragma unroll
    for (int i = 0; i < 4; ++i){
        int nr = n0 + ksub*4 + i;
        if (nr < NN) eall[(size_t)nr*16 + r16] = acc[i];
    }
}

__global__ void k_hist(const int* __restrict__ didx, unsigned* __restrict__ cnt){
    int gid = blockIdx.x*blockDim.x + threadIdx.x;
    if (gid >= RR*EE) return;
    int r = gid / EE;
    atomicAdd(&cnt[(size_t)r*NN + didx[gid]], 1u);
}

// segment base allocation: wave-scan + one cursor atomic per wave (order-free CSR)
__global__ void k_alloc(const unsigned* __restrict__ cnt, unsigned* __restrict__ base,
                        unsigned* __restrict__ cursor){
    int gid = blockIdx.x*blockDim.x + threadIdx.x;
    int lane = threadIdx.x & 63;
    unsigned c = (gid < RR*NN) ? cnt[gid] : 0u;
    unsigned x = c;
    #pragma unroll
    for (int off = 1; off < 64; off <<= 1){
        unsigned t = __shfl_up(x, off, 64);
        if (lane >= off) x += t;
    }
    unsigned wtotal = __shfl(x, 63, 64);
    unsigned wbase = 0u;
    if (lane == 63) wbase = atomicAdd(cursor, wtotal);
    wbase = __shfl(wbase, 63, 64);
    if (gid < RR*NN) base[gid] = wbase + x - c;
}

// scatter src + packed f16 el[4 heads] into dst-grouped slots
__global__ void k_scatter(const int* __restrict__ sidx, const int* __restrict__ didx,
                          const float* __restrict__ eall,
                          const unsigned* __restrict__ base, unsigned* __restrict__ cur,
                          int* __restrict__ esrc, uint2* __restrict__ epak){
    int gid = blockIdx.x*blockDim.x + threadIdx.x;
    if (gid >= RR*EE) return;
    int r = gid / EE;
    int s = sidx[gid];
    size_t rn = (size_t)r*NN + didx[gid];
    unsigned pos = base[rn] + atomicAdd(&cur[rn], 1u);
    esrc[pos] = s;
    float4 e4 = *(const float4*)(eall + (size_t)s*16 + r*8);
    h2 p0 = __builtin_amdgcn_cvt_pkrtz(e4.x, e4.y);
    h2 p1 = __builtin_amdgcn_cvt_pkrtz(e4.z, e4.w);
    uint2 u;
    u.x = *(unsigned*)&p0; u.y = *(unsigned*)&p1;
    epak[pos] = u;
}

// bf16 MFMA GEMM: fsall[M,512] = x[M,256] @ Wt^T (both relations).
// A: f32 reg-staged -> bf16, swizzled ds_write. B: global_load_lds, pre-swizzled src.
__global__ __launch_bounds__(256) void k_gemm(const float* __restrict__ Ax,
                                              const ushort* __restrict__ Bt,
                                              ushort* __restrict__ C){
    __shared__ ushort Ab[128*64];
    __shared__ ushort Bb[128*64];
    int tid = threadIdx.x;
    int w = tid >> 6, lane = tid & 63;
    int m0 = blockIdx.x * 128;
    int n0 = blockIdx.y * 128;
    int wm = w >> 1, wn = w & 1;      // 2x2 wave grid, 64x64 per wave
    f32x4 acc[4][4] = {};
    int srow  = lane >> 3;            // row within 8-row chunk
    int sunit = (lane & 7) ^ srow;    // pre-swizzled source 16B unit

    for (int k0 = 0; k0 < KK; k0 += 64){
        // stage A: f32 -> bf16, swizzled ds_write_b64
        #pragma unroll
        for (int i = 0; i < 8; ++i){
            int flat = tid + 256*i;           // 0..2047
            int row  = flat >> 4;             // 0..127
            int q    = flat & 15;             // float4 index within row
            int arw = m0 + row; if (arw >= NN) arw = NN-1;
            float4 v = *(const float4*)(Ax + (size_t)arw*KK + k0 + q*4);
            ushort4 b;
            b.x = f2bf(v.x); b.y = f2bf(v.y); b.z = f2bf(v.z); b.w = f2bf(v.w);
            int usw = (q >> 1) ^ (row & 7);
            *(ushort4*)((char*)Ab + row*128 + usw*16 + (q & 1)*8) = b;
        }
        // stage B: global_load_lds 16B, wave-uniform LDS base, pre-swizzled source
        #pragma unroll
        for (int i = 0; i < 4; ++i){
            int rowl = i*32 + w*8 + srow;     // n-index 0..127 (per-lane source row)
            const ushort* gb = Bt + (size_t)(n0 + rowl)*KK + k0 + sunit*8;
            __builtin_amdgcn_global_load_lds(
                (const __attribute__((address_space(1))) void*)gb,
                (__attribute__((address_space(3))) void*)(Bb + (i*32 + w*8)*64),
                16, 0, 0);
        }
        __syncthreads();
        #pragma unroll
        for (int kk = 0; kk < 64; kk += 32){
            bfx8 af[4], bfr[4];
            int r16 = lane & 15;
            int ublk = (lane >> 4) + (kk >> 3);   // logical 16B unit 0..7
            #pragma unroll
            for (int m = 0; m < 4; ++m){
                int row = wm*64 + m*16 + r16;
                af[m] = *(const bfx8*)(Ab + row*64 + ((ublk ^ (row & 7)) << 3));
            }
            #pragma unroll
            for (int n = 0; n < 4; ++n){
                int col = wn*64 + n*16 + r16;
                bfr[n] = *(const bfx8*)(Bb + col*64 + ((ublk ^ (col & 7)) << 3));
            }
            #pragma unroll
            for (int m = 0; m < 4; ++m)
                #pragma unroll
                for (int n = 0; n < 4; ++n)
                    acc[m][n] = __builtin_amdgcn_mfma_f32_16x16x32_bf16(
                                    af[m], bfr[n], acc[m][n], 0, 0, 0);
        }
        __syncthreads();
    }
    // epilogue: C/D layout col=lane&15, row=(lane>>4)*4+i ; store bf16, stride 512
    int cr = lane >> 4, cc = lane & 15;
    #pragma unroll
    for (int m = 0; m < 4; ++m){
        #pragma unroll
        for (int i = 0; i < 4; ++i){
            int row = m0 + wm*64 + m*16 + cr*4 + i;
            #pragma unroll
            for (int n = 0; n < 4; ++n)
                C[(size_t)row*HD2 + n0 + wn*64 + n*16 + cc] = f2bf(acc[m][n][i]);
        }
    }
}

// one wave per node, both relations; feature-per-lane (4 f32/lane).
// MINIMAL-VGPR simple loop (R5's 145µs structure): occupancy is the lever for
// this latency-bound gather (R6/R10 showed unroll->44 VGPR->47% occ = slower).
// + no-max softmax (no serial rescale chain, logits bounded ~±6)
// + epak f16 el stream (replaces random eall[src] gather; FETCH -16% in R10)
// + nt-store on out (don't evict fsall from L3).
__global__ __launch_bounds__(256) void k_agg(const unsigned* __restrict__ base,
                                             const unsigned* __restrict__ cnt,
                                             const int* __restrict__ esrc,
                                             const uint2* __restrict__ epak,
                                             const float* __restrict__ eall,
                                             const ushort* __restrict__ fsall,
                                             const float* __restrict__ bias,
                                             float* __restrict__ out){
    int w = threadIdx.x >> 6, lane = threadIdx.x & 63;
    int n = blockIdx.x*4 + w;
    int h = lane >> 4;
    float rx = 0.f, ry = 0.f, rz = 0.f, rw = 0.f;
    #pragma unroll
    for (int r = 0; r < RR; ++r){
        unsigned beg = base[(size_t)r*NN + n], num = cnt[(size_t)r*NN + n];
        float er = eall[(size_t)n*16 + r*8 + 4 + h];
        float den = 0.f;
        float ax = 0.f, ay = 0.f, az = 0.f, aw = 0.f;
        for (unsigned u = beg; u < beg + num; ++u){
            int s = esrc[u];
            uint2 ep = epak[u];
            unsigned wsel = (h & 2) ? ep.y : ep.x;
            ushort hv = (h & 1) ? (ushort)(wsel >> 16) : (ushort)wsel;
            __fp16 hf = *(__fp16*)&hv;
            float v = (float)hf + er;
            v = v > 0.f ? v : NEG_SLOPE*v;
            float p = __expf(v);
            ushort4 f = *(const ushort4*)(fsall + (size_t)s*HD2 + r*HD + lane*4);
            den += p;
            ax += p*bf2f(f.x); ay += p*bf2f(f.y);
            az += p*bf2f(f.z); aw += p*bf2f(f.w);
        }
        float inv = den > 0.f ? 1.f/den : 0.f;
        rx += ax*inv; ry += ay*inv;
        rz += az*inv; rw += aw*inv;
    }
    const float4 b0 = *(const float4*)(bias + lane*4);
    const float4 b1 = *(const float4*)(bias + HD + lane*4);
    f32x4 res;
    res[0] = rx + b0.x + b1.x; res[1] = ry + b0.y + b1.y;
    res[2] = rz + b0.z + b1.z; res[3] = rw + b0.w + b1.w;
    __builtin_nontemporal_store(res, (f32x4*)(out + (size_t)n*HD + lane*4));
}

extern "C" void kernel_launch(void* const* d_in, const int* in_sizes, int n_in,
                              void* d_out, int out_size, void* d_ws, size_t ws_size,
                              hipStream_t stream) {
    const float* x     = (const float*)d_in[0];
    const float* W_src = (const float*)d_in[1];
    const float* W_dst = (const float*)d_in[2];
    const float* al    = (const float*)d_in[3];
    const float* ar    = (const float*)d_in[4];
    const float* bias  = (const float*)d_in[5];
    const int*   sidx  = (const int*)d_in[6];
    const int*   didx  = (const int*)d_in[7];
    float* out = (float*)d_out;

    // workspace carve-up (~123.5 MB)
    ushort*   fsall  = (ushort*)d_ws;                        // NNP*512 bf16
    ushort*   Wt     = fsall + (size_t)NNP*HD2;              // 512*256 bf16
    ushort*   wcatbT = Wt + (size_t)RR*KK*HD;                // 16*256 bf16
    float*    eall   = (float*)(wcatbT + 16*KK);             // N*16 f32
    unsigned* cnt    = (unsigned*)(eall + (size_t)NN*16);    // R*N
    unsigned* cur    = cnt + (size_t)RR*NN;                  // R*N
    unsigned* cursor = cur + (size_t)RR*NN;                  // 8 (1 + pad)
    unsigned* base   = cursor + 8;                           // R*N
    int*      esrc   = (int*)(base + (size_t)RR*NN);         // R*E ints
    uint2*    epak   = (uint2*)(esrc + (size_t)RR*EE);       // R*E uint2

    k_wcat<<<(KK*16 + 255)/256, 256, 0, stream>>>(W_src, W_dst, al, ar, wcatbT);
    k_castW<<<(RR*KK*HD + 255)/256, 256, 0, stream>>>(W_src, Wt);
    k_eall<<<(NNP + 63)/64, 256, 0, stream>>>(x, wcatbT, eall);
    k_gemm<<<dim3((NNP + 127)/128, HD2/128), 256, 0, stream>>>(x, Wt, fsall);

    (void)hipMemsetAsync(cnt, 0, (size_t)(2*RR*NN + 8)*4, stream);   // cnt, cur, cursor
    k_hist<<<(RR*EE + 255)/256, 256, 0, stream>>>(didx, cnt);
    k_alloc<<<(RR*NN + 255)/256, 256, 0, stream>>>(cnt, base, cursor);
    k_scatter<<<(RR*EE + 255)/256, 256, 0, stream>>>(sidx, didx, eall, base, cur, esrc, epak);

    k_agg<<<NN/4, 256, 0, stream>>>(base, cnt, esrc, epak, eall, fsall, bias, out);
}

// Round 12
// 365.872 us; speedup vs baseline: 1.1899x; 1.0191x over previous
//
#include <hip/hip_runtime.h>
#include <hip/hip_bf16.h>

#define NN 100000   // nodes
#define NNP 100032  // NN padded to 64
#define HH 4        // heads
#define DD 64       // dim per head
#define RR 2        // relations
#define EE 500000   // edges per relation
#define KK 256      // in_feat
#define HD 256      // H*D
#define HD2 512     // both relations' features per node
#define NEG_SLOPE 0.2f

typedef __attribute__((ext_vector_type(8))) short bfx8;
typedef __attribute__((ext_vector_type(4))) float f32x4;
typedef __attribute__((ext_vector_type(2))) __fp16 h2;

__device__ __forceinline__ ushort f2bf(float f){
    __hip_bfloat16 h = __float2bfloat16(f);
    return *(ushort*)&h;
}
__device__ __forceinline__ float bf2f(ushort u){
    return __uint_as_float(((unsigned)u) << 16);
}

// fused: Wt[r*256+n][k] = bf16(W_src[r][k][n])  AND  (gid<KK*16) wcatbT[j][k]
__global__ void k_prep(const float* __restrict__ Ws, const float* __restrict__ Wd,
                       const float* __restrict__ al, const float* __restrict__ ar,
                       ushort* __restrict__ Wt, ushort* __restrict__ wcatbT){
    int gid = blockIdx.x*blockDim.x + threadIdx.x;
    if (gid >= RR*KK*HD) return;
    int r = gid >> 16;
    int idx = gid & 65535;
    int n = idx >> 8, k = idx & 255;
    Wt[gid] = f2bf(Ws[((size_t)r*KK + k)*HD + n]);
    if (gid < KK*16){
        int kw = gid >> 4, j = gid & 15;
        int rw = j >> 3, s = (j >> 2) & 1, h = j & 3;
        const float* w = (s ? Wd : Ws) + ((size_t)rw*KK + kw)*HD + h*DD;
        const float* a = (s ? ar : al) + (size_t)(rw*HH + h)*DD;
        float acc = 0.f;
        #pragma unroll 8
        for (int d=0; d<DD; ++d) acc += w[d]*a[d];
        wcatbT[(size_t)j*KK + kw] = f2bf(acc);
    }
}

__global__ void k_hist(const int* __restrict__ didx, unsigned* __restrict__ cnt){
    int gid = blockIdx.x*blockDim.x + threadIdx.x;
    if (gid >= RR*EE) return;
    int r = gid / EE;
    atomicAdd(&cnt[(size_t)r*NN + didx[gid]], 1u);
}

// segment base allocation: wave-scan + one cursor atomic per wave (order-free CSR)
__global__ void k_alloc(const unsigned* __restrict__ cnt, unsigned* __restrict__ base,
                        unsigned* __restrict__ cursor){
    int gid = blockIdx.x*blockDim.x + threadIdx.x;
    int lane = threadIdx.x & 63;
    unsigned c = (gid < RR*NN) ? cnt[gid] : 0u;
    unsigned x = c;
    #pragma unroll
    for (int off = 1; off < 64; off <<= 1){
        unsigned t = __shfl_up(x, off, 64);
        if (lane >= off) x += t;
    }
    unsigned wtotal = __shfl(x, 63, 64);
    unsigned wbase = 0u;
    if (lane == 63) wbase = atomicAdd(cursor, wtotal);
    wbase = __shfl(wbase, 63, 64);
    if (gid < RR*NN) base[gid] = wbase + x - c;
}

// scatter src + packed f16 el[4 heads] into dst-grouped slots
__global__ void k_scatter(const int* __restrict__ sidx, const int* __restrict__ didx,
                          const float* __restrict__ eall,
                          const unsigned* __restrict__ base, unsigned* __restrict__ cur,
                          int* __restrict__ esrc, uint2* __restrict__ epak){
    int gid = blockIdx.x*blockDim.x + threadIdx.x;
    if (gid >= RR*EE) return;
    int r = gid / EE;
    int s = sidx[gid];
    size_t rn = (size_t)r*NN + didx[gid];
    unsigned pos = base[rn] + atomicAdd(&cur[rn], 1u);
    esrc[pos] = s;
    float4 e4 = *(const float4*)(eall + (size_t)s*16 + r*8);
    h2 p0 = __builtin_amdgcn_cvt_pkrtz(e4.x, e4.y);
    h2 p1 = __builtin_amdgcn_cvt_pkrtz(e4.z, e4.w);
    uint2 u;
    u.x = *(unsigned*)&p0; u.y = *(unsigned*)&p1;
    epak[pos] = u;
}

// bf16 MFMA GEMM: fsall[M,512] = x[M,256] @ Wt^T (both relations), PLUS
// fused eall = x @ wcat computed by (n0==0, wn==0) waves from the same staged
// A-tiles (identical MFMA chain to the old k_eall -> bit-identical eall).
// A: f32 reg-staged -> bf16, swizzled ds_write. B: global_load_lds, pre-swizzled src.
__global__ __launch_bounds__(256) void k_gemm(const float* __restrict__ Ax,
                                              const ushort* __restrict__ Bt,
                                              const ushort* __restrict__ wcatbT,
                                              ushort* __restrict__ C,
                                              float* __restrict__ eall){
    __shared__ ushort Ab[128*64];
    __shared__ ushort Bb[128*64];
    int tid = threadIdx.x;
    int w = tid >> 6, lane = tid & 63;
    int m0 = blockIdx.x * 128;
    int n0 = blockIdx.y * 128;
    int wm = w >> 1, wn = w & 1;      // 2x2 wave grid, 64x64 per wave
    int r16 = lane & 15, ksub = lane >> 4;
    f32x4 acc[4][4] = {};
    f32x4 acc_e[4] = {};
    bool doE = (n0 == 0) && (wn == 0);
    int srow  = lane >> 3;            // row within 8-row chunk
    int sunit = (lane & 7) ^ srow;    // pre-swizzled source 16B unit

    for (int k0 = 0; k0 < KK; k0 += 64){
        // stage A: f32 -> bf16, swizzled ds_write_b64
        #pragma unroll
        for (int i = 0; i < 8; ++i){
            int flat = tid + 256*i;           // 0..2047
            int row  = flat >> 4;             // 0..127
            int q    = flat & 15;             // float4 index within row
            int arw = m0 + row; if (arw >= NN) arw = NN-1;
            float4 v = *(const float4*)(Ax + (size_t)arw*KK + k0 + q*4);
            ushort4 b;
            b.x = f2bf(v.x); b.y = f2bf(v.y); b.z = f2bf(v.z); b.w = f2bf(v.w);
            int usw = (q >> 1) ^ (row & 7);
            *(ushort4*)((char*)Ab + row*128 + usw*16 + (q & 1)*8) = b;
        }
        // stage B: global_load_lds 16B, wave-uniform LDS base, pre-swizzled source
        #pragma unroll
        for (int i = 0; i < 4; ++i){
            int rowl = i*32 + w*8 + srow;     // n-index 0..127 (per-lane source row)
            const ushort* gb = Bt + (size_t)(n0 + rowl)*KK + k0 + sunit*8;
            __builtin_amdgcn_global_load_lds(
                (const __attribute__((address_space(1))) void*)gb,
                (__attribute__((address_space(3))) void*)(Bb + (i*32 + w*8)*64),
                16, 0, 0);
        }
        __syncthreads();
        #pragma unroll
        for (int kk = 0; kk < 64; kk += 32){
            bfx8 af[4], bfr[4];
            int ublk = ksub + (kk >> 3);          // logical 16B unit 0..7
            #pragma unroll
            for (int m = 0; m < 4; ++m){
                int row = wm*64 + m*16 + r16;
                af[m] = *(const bfx8*)(Ab + row*64 + ((ublk ^ (row & 7)) << 3));
            }
            #pragma unroll
            for (int n = 0; n < 4; ++n){
                int col = wn*64 + n*16 + r16;
                bfr[n] = *(const bfx8*)(Bb + col*64 + ((ublk ^ (col & 7)) << 3));
            }
            #pragma unroll
            for (int m = 0; m < 4; ++m)
                #pragma unroll
                for (int n = 0; n < 4; ++n)
                    acc[m][n] = __builtin_amdgcn_mfma_f32_16x16x32_bf16(
                                    af[m], bfr[n], acc[m][n], 0, 0, 0);
            if (doE){
                bfx8 be = *(const bfx8*)(wcatbT + (size_t)r16*KK + k0 + kk + ksub*8);
                #pragma unroll
                for (int m = 0; m < 4; ++m)
                    acc_e[m] = __builtin_amdgcn_mfma_f32_16x16x32_bf16(
                                    af[m], be, acc_e[m], 0, 0, 0);
            }
        }
        __syncthreads();
    }
    // epilogue: C/D layout col=lane&15, row=(lane>>4)*4+i ; store bf16, stride 512
    int cr = ksub, cc = r16;
    #pragma unroll
    for (int m = 0; m < 4; ++m){
        #pragma unroll
        for (int i = 0; i < 4; ++i){
            int row = m0 + wm*64 + m*16 + cr*4 + i;
            #pragma unroll
            for (int n = 0; n < 4; ++n)
                C[(size_t)row*HD2 + n0 + wn*64 + n*16 + cc] = f2bf(acc[m][n][i]);
        }
    }
    if (doE){
        #pragma unroll
        for (int m = 0; m < 4; ++m){
            #pragma unroll
            for (int i = 0; i < 4; ++i){
                int row = m0 + wm*64 + m*16 + cr*4 + i;
                if (row < NN) eall[(size_t)row*16 + cc] = acc_e[m][i];
            }
        }
    }
}

// one wave per node, both relations; feature-per-lane (4 f32/lane).
// MINIMAL-VGPR simple loop (occupancy is the lever for this latency-bound
// gather; R6/R10 showed unroll->44 VGPR->47% occ = slower).
// + no-max softmax (no serial rescale chain, logits bounded ~±6)
// + epak f16 el stream (replaces random eall[src] gather)
// + nt-store on out. k_agg runs at the random-64B-gather HBM ceiling (~2.85 TB/s).
__global__ __launch_bounds__(256) void k_agg(const unsigned* __restrict__ base,
                                             const unsigned* __restrict__ cnt,
                                             const int* __restrict__ esrc,
                                             const uint2* __restrict__ epak,
                                             const float* __restrict__ eall,
                                             const ushort* __restrict__ fsall,
                                             const float* __restrict__ bias,
                                             float* __restrict__ out){
    int w = threadIdx.x >> 6, lane = threadIdx.x & 63;
    int n = blockIdx.x*4 + w;
    int h = lane >> 4;
    float rx = 0.f, ry = 0.f, rz = 0.f, rw = 0.f;
    #pragma unroll
    for (int r = 0; r < RR; ++r){
        unsigned beg = base[(size_t)r*NN + n], num = cnt[(size_t)r*NN + n];
        float er = eall[(size_t)n*16 + r*8 + 4 + h];
        float den = 0.f;
        float ax = 0.f, ay = 0.f, az = 0.f, aw = 0.f;
        for (unsigned u = beg; u < beg + num; ++u){
            int s = esrc[u];
            uint2 ep = epak[u];
            unsigned wsel = (h & 2) ? ep.y : ep.x;
            ushort hv = (h & 1) ? (ushort)(wsel >> 16) : (ushort)wsel;
            __fp16 hf = *(__fp16*)&hv;
            float v = (float)hf + er;
            v = v > 0.f ? v : NEG_SLOPE*v;
            float p = __expf(v);
            ushort4 f = *(const ushort4*)(fsall + (size_t)s*HD2 + r*HD + lane*4);
            den += p;
            ax += p*bf2f(f.x); ay += p*bf2f(f.y);
            az += p*bf2f(f.z); aw += p*bf2f(f.w);
        }
        float inv = den > 0.f ? 1.f/den : 0.f;
        rx += ax*inv; ry += ay*inv;
        rz += az*inv; rw += aw*inv;
    }
    const float4 b0 = *(const float4*)(bias + lane*4);
    const float4 b1 = *(const float4*)(bias + HD + lane*4);
    f32x4 res;
    res[0] = rx + b0.x + b1.x; res[1] = ry + b0.y + b1.y;
    res[2] = rz + b0.z + b1.z; res[3] = rw + b0.w + b1.w;
    __builtin_nontemporal_store(res, (f32x4*)(out + (size_t)n*HD + lane*4));
}

extern "C" void kernel_launch(void* const* d_in, const int* in_sizes, int n_in,
                              void* d_out, int out_size, void* d_ws, size_t ws_size,
                              hipStream_t stream) {
    const float* x     = (const float*)d_in[0];
    const float* W_src = (const float*)d_in[1];
    const float* W_dst = (const float*)d_in[2];
    const float* al    = (const float*)d_in[3];
    const float* ar    = (const float*)d_in[4];
    const float* bias  = (const float*)d_in[5];
    const int*   sidx  = (const int*)d_in[6];
    const int*   didx  = (const int*)d_in[7];
    float* out = (float*)d_out;

    // workspace carve-up (~123.5 MB)
    ushort*   fsall  = (ushort*)d_ws;                        // NNP*512 bf16
    ushort*   Wt     = fsall + (size_t)NNP*HD2;              // 512*256 bf16
    ushort*   wcatbT = Wt + (size_t)RR*KK*HD;                // 16*256 bf16
    float*    eall   = (float*)(wcatbT + 16*KK);             // N*16 f32
    unsigned* cnt    = (unsigned*)(eall + (size_t)NN*16);    // R*N
    unsigned* cur    = cnt + (size_t)RR*NN;                  // R*N
    unsigned* cursor = cur + (size_t)RR*NN;                  // 8 (1 + pad)
    unsigned* base   = cursor + 8;                           // R*N
    int*      esrc   = (int*)(base + (size_t)RR*NN);         // R*E ints
    uint2*    epak   = (uint2*)(esrc + (size_t)RR*EE);       // R*E uint2

    k_prep<<<(RR*KK*HD + 255)/256, 256, 0, stream>>>(W_src, W_dst, al, ar, Wt, wcatbT);
    k_gemm<<<dim3((NNP + 127)/128, HD2/128), 256, 0, stream>>>(x, Wt, wcatbT, fsall, eall);

    (void)hipMemsetAsync(cnt, 0, (size_t)(2*RR*NN + 8)*4, stream);   // cnt, cur, cursor
    k_hist<<<(RR*EE + 255)/256, 256, 0, stream>>>(didx, cnt);
    k_alloc<<<(RR*NN + 255)/256, 256, 0, stream>>>(cnt, base, cursor);
    k_scatter<<<(RR*EE + 255)/256, 256, 0, stream>>>(sidx, didx, eall, base, cur, esrc, epak);

    k_agg<<<NN/4, 256, 0, stream>>>(base, cnt, esrc, epak, eall, fsall, bias, out);
}